// Round 13
// baseline (753.657 us; speedup 1.0000x reference)
//
#include <hip/hip_runtime.h>
#include <stdint.h>

typedef unsigned short u16;
typedef uint32_t u32;
typedef __attribute__((ext_vector_type(8))) short bf16x8;   // 8 bf16 (4 VGPRs)
typedef __attribute__((ext_vector_type(4))) float f32x4;
typedef __attribute__((ext_vector_type(4))) short short4v;
typedef __attribute__((ext_vector_type(8))) short short8v;
typedef __attribute__((ext_vector_type(4))) float float4v;

#define MFMA(a, b, c) __builtin_amdgcn_mfma_f32_16x16x32_bf16(a, b, c, 0, 0, 0)

__device__ __forceinline__ u16 f2bf(float f) {
  u32 u = __builtin_bit_cast(u32, f);
  u += 0x7FFFu + ((u >> 16) & 1u);  // RNE
  return (u16)(u >> 16);
}

// split: f ~= hi + lo, hi = truncated-bf16(f), lo = RNE-bf16(f - hi). |err| <= 2^-17 |f|
__device__ __forceinline__ void fsplit(float f, u16& hi, u16& lo) {
  u32 u = __builtin_bit_cast(u32, f);
  hi = (u16)(u >> 16);
  float fhi = __builtin_bit_cast(float, u & 0xFFFF0000u);
  lo = f2bf(f - fhi);  // exact subtraction (mantissa prefix)
}

__device__ __forceinline__ void load_lds16(const void* g, void* lds) {
  // width-16 direct global->LDS; dest = wave-uniform base, HW adds lane*16
  __builtin_amdgcn_global_load_lds((const __attribute__((address_space(1))) void*)g,
                                   (__attribute__((address_space(3))) void*)lds, 16, 0, 0);
}

// ---------------- convert fp32 -> (hi,lo) bf16 pair (x + 4 weights) ----------------
struct CvtArgsP {
  const float* src[5];
  u16* dhi[5];
  u16* dlo[5];
};

__global__ __launch_bounds__(256) void convert_split_p(CvtArgsP a) {
  const size_t NX = 16777216u;  // B*T*N*512
  const size_t NW = 262144u;    // 512*512
  size_t t8 = ((size_t)blockIdx.x * 256 + threadIdx.x) * 8;
  int seg;
  size_t off;
  if (t8 < NX) {
    seg = 0; off = t8;
  } else {
    size_t r = t8 - NX;
    seg = 1 + (int)(r >> 18);
    off = r & (NW - 1);
  }
  const float* s = a.src[seg] + off;
  float4v v0 = *((const float4v*)s);
  float4v v1 = *((const float4v*)(s + 4));
  short8v oh, ol;
  u16 h, l;
  fsplit(v0[0], h, l); oh[0] = (short)h; ol[0] = (short)l;
  fsplit(v0[1], h, l); oh[1] = (short)h; ol[1] = (short)l;
  fsplit(v0[2], h, l); oh[2] = (short)h; ol[2] = (short)l;
  fsplit(v0[3], h, l); oh[3] = (short)h; ol[3] = (short)l;
  fsplit(v1[0], h, l); oh[4] = (short)h; ol[4] = (short)l;
  fsplit(v1[1], h, l); oh[5] = (short)h; ol[5] = (short)l;
  fsplit(v1[2], h, l); oh[6] = (short)h; ol[6] = (short)l;
  fsplit(v1[3], h, l); oh[7] = (short)h; ol[7] = (short)l;
  *((short8v*)(a.dhi[seg] + off)) = oh;
  *((short8v*)(a.dlo[seg] + off)) = ol;
}

// ---------------- 3-term split-bf16 GEMM: C = A*B^T, A=(Ahi+Alo), B=(Bhi+Blo) ----
// m97 structure, 24 K-phases: kt 0-7 Ahi*Bhi, 8-15 Ahi*Blo, 16-23 Alo*Bhi
// (dropped Alo*Blo ~ 2^-16). M = 8192 per launch (one batch).
// MODE 0: (hi,lo) row-major out; MODE 1: fp32 row-major out; MODE 2: (hi,lo) v_t out.
template <int MODE>
__global__ __launch_bounds__(256) void gemm3_p(const u16* __restrict__ Ahi,
                                               const u16* __restrict__ Alo,
                                               const u16* __restrict__ Bhi,
                                               const u16* __restrict__ Blo,
                                               void* __restrict__ Cph,
                                               void* __restrict__ Cpl) {
  __shared__ u16 lA[128 * 64];
  __shared__ u16 lB[128 * 64];
  const int tid = threadIdx.x;
  const int wave = tid >> 6, lane = tid & 63;
  const int g = lane >> 4, li = lane & 15;
  const int wr = wave >> 1, wc = wave & 1;
  const int m0 = blockIdx.x * 128, n0 = blockIdx.y * 128;
  const int rowa = tid >> 3, cl = tid & 7;

  f32x4 acc[4][4] = {};

  for (int kt = 0; kt < 24; ++kt) {
    const u16* As = (kt < 16) ? Ahi : Alo;
    const u16* Bs = (kt < 8) ? Bhi : ((kt < 16) ? Blo : Bhi);
    const int kk = (kt & 7) * 64;
    __syncthreads();
#pragma unroll
    for (int it = 0; it < 4; ++it) {
      const int r = it * 32 + rowa;
      const int sc = (cl ^ (r & 7)) * 8;  // pre-swizzled source chunk (rule #21)
      load_lds16(As + (size_t)(m0 + r) * 512 + kk + sc,
                 lA + (it * 256 + wave * 64) * 8);
      load_lds16(Bs + (size_t)(n0 + r) * 512 + kk + sc,
                 lB + (it * 256 + wave * 64) * 8);
    }
    __syncthreads();
#pragma unroll
    for (int ks = 0; ks < 2; ++ks) {
      bf16x8 af[4], bf[4];
#pragma unroll
      for (int mi = 0; mi < 4; ++mi) {
        const int r = wr * 64 + mi * 16 + li;
        af[mi] = *(const bf16x8*)(lA + r * 64 + (((ks * 4 + g) ^ (r & 7)) * 8));
      }
#pragma unroll
      for (int ni = 0; ni < 4; ++ni) {
        const int r = wc * 64 + ni * 16 + li;
        bf[ni] = *(const bf16x8*)(lB + r * 64 + (((ks * 4 + g) ^ (r & 7)) * 8));
      }
#pragma unroll
      for (int mi = 0; mi < 4; ++mi)
#pragma unroll
        for (int ni = 0; ni < 4; ++ni)
          acc[mi][ni] = MFMA(af[mi], bf[ni], acc[mi][ni]);
    }
  }

  if constexpr (MODE == 0) {
    u16* Ch = (u16*)Cph;
    u16* Cl = (u16*)Cpl;
#pragma unroll
    for (int mi = 0; mi < 4; ++mi)
#pragma unroll
      for (int ni = 0; ni < 4; ++ni) {
        const int col = n0 + wc * 64 + ni * 16 + li;
        const int row0 = m0 + wr * 64 + mi * 16 + g * 4;
#pragma unroll
        for (int r = 0; r < 4; ++r) {
          u16 h, l;
          fsplit(acc[mi][ni][r], h, l);
          const size_t idx = (size_t)(row0 + r) * 512 + col;
          Ch[idx] = h;
          Cl[idx] = l;
        }
      }
  } else if constexpr (MODE == 1) {
    float* C = (float*)Cph;
#pragma unroll
    for (int mi = 0; mi < 4; ++mi)
#pragma unroll
      for (int ni = 0; ni < 4; ++ni) {
        const int col = n0 + wc * 64 + ni * 16 + li;
        const int row0 = m0 + wr * 64 + mi * 16 + g * 4;
#pragma unroll
        for (int r = 0; r < 4; ++r)
          C[(size_t)(row0 + r) * 512 + col] = acc[mi][ni][r];
      }
  } else {
    u16* Ch = (u16*)Cph;
    u16* Cl = (u16*)Cpl;
#pragma unroll
    for (int mi = 0; mi < 4; ++mi)
#pragma unroll
      for (int ni = 0; ni < 4; ++ni) {
        const int col = n0 + wc * 64 + ni * 16 + li;
        const int hh = col >> 6, c = col & 63;
        const int row0 = m0 + wr * 64 + mi * 16 + g * 4;
        const int bt = row0 >> 6, n = row0 & 63;   // bt = local t within batch
        short4v ph, pl;
#pragma unroll
        for (int r = 0; r < 4; ++r) {
          u16 h, l;
          fsplit(acc[mi][ni][r], h, l);
          ph[r] = (short)h;
          pl[r] = (short)l;
        }
        const size_t idx = ((size_t)bt * 8 + hh) * 4096 + (size_t)c * 64 + n;
        *(short4v*)(Ch + idx) = ph;
        *(short4v*)(Cl + idx) = pl;
      }
  }
}

// ---------------- attention (ONE BATCH): one BLOCK per (t,h), waves split i ----
// Round-6 structure, 3-term split MFMA. Y aliases Q (each block is the sole
// reader of its Q slice and reads it into registers before writing Y there) —
// so q/Y params carry NO __restrict__.
__global__ __launch_bounds__(256) void attn_kernel_p(const u16* qhi,
                                                     const u16* qlo,
                                                     const u16* __restrict__ khi,
                                                     const u16* __restrict__ klo,
                                                     const u16* __restrict__ vthi,
                                                     const u16* __restrict__ vtlo,
                                                     u16* Yhi,
                                                     u16* Ylo) {
  __shared__ __align__(16) char lds[81920];  // 2 x 32KB (Khi,Klo,Vhi,Vlo) dbuf + 4 x 4KB P(hi,lo)
  const int tid = threadIdx.x;
  const int wave = tid >> 6, lane = tid & 63;
  const int g = lane >> 4, li = lane & 15;
  const int bid = blockIdx.x;  // 0..1023
  const int h = bid & 7, t = bid >> 3;
  char* pbh = lds + 65536 + wave * 4096;
  char* pbl = pbh + 2048;
  const int i0 = wave * 16;
  const int sub = lane >> 3, cl = lane & 7;

  // Q fragments: lane(g,li) holds Q[i0+li][ks*32+g*8 + 0..7], hi and lo
  const size_t qoff = ((size_t)(t * 64 + i0 + li)) * 512 + h * 64;
  bf16x8 qfh[2], qfl[2];
#pragma unroll
  for (int ks = 0; ks < 2; ++ks) {
    qfh[ks] = *(const bf16x8*)(qhi + qoff + ks * 32 + g * 8);
    qfl[ks] = *(const bf16x8*)(qlo + qoff + ks * 32 + g * 8);
  }

  f32x4 accO[4] = {};  // [fc]; lane(g,li): O[i=i0+g*4+r][c=fc*16+li]
  const int lmax = (t < 12) ? t : 12;

  // stage: wave w loads array w (0:Khi 1:Klo 2:Vhi 3:Vlo), 8 chunks of 8 rows
  auto stage = [&](int st, int cur) {
    char* base = lds + cur * 32768 + wave * 8192;
    const u16* karr = (wave == 0) ? khi : klo;
    const u16* varr = (wave == 2) ? vthi : vtlo;
    const size_t koff = ((size_t)(st * 64)) * 512 + h * 64;
    const size_t voff = ((size_t)(st * 8 + h)) * 4096;
#pragma unroll
    for (int m = 0; m < 8; ++m) {
      const int r = m * 8 + sub;
      if (wave < 2) {  // K rows j = r, row stride 512
        load_lds16(karr + koff + (size_t)r * 512 + (cl ^ (r & 7)) * 8,
                   base + m * 1024);
      } else {         // V^T rows c = r, contiguous 4096
        load_lds16(varr + voff + r * 64 + (cl ^ (r & 7)) * 8,
                   base + m * 1024);
      }
    }
  };

  if (lmax >= 2) {
    stage(t - 2, 0);
    int cur = 0;
    for (int lag = 2; lag <= lmax; ++lag) {
      __syncthreads();  // drains each wave's staging loads + syncs buffers
      if (lag < lmax) stage(t - lag - 1, cur ^ 1);  // prefetch next under compute

      const u16* Kh = (const u16*)(lds + cur * 32768);
      const u16* Kl = Kh + 4096;
      const u16* Vh = Kh + 8192;
      const u16* Vl = Kh + 12288;

      // S^T, 3-term: 24 MFMAs
      f32x4 S[4] = {};
#pragma unroll
      for (int ks = 0; ks < 2; ++ks)
#pragma unroll
        for (int fj = 0; fj < 4; ++fj) {
          const int j = fj * 16 + li;
          const int off = j * 64 + (((ks * 4 + g) ^ (j & 7)) * 8);
          bf16x8 kh = *(const bf16x8*)(Kh + off);
          bf16x8 kl = *(const bf16x8*)(Kl + off);
          S[fj] = MFMA(kh, qfh[ks], S[fj]);
          S[fj] = MFMA(kl, qfh[ks], S[fj]);
          S[fj] = MFMA(kh, qfl[ks], S[fj]);
        }

      // row softmax over j (round-6 proven path)
      float mx = S[0][0];
#pragma unroll
      for (int fj = 0; fj < 4; ++fj)
#pragma unroll
        for (int r = 0; r < 4; ++r) mx = fmaxf(mx, S[fj][r]);
      mx = fmaxf(mx, __shfl_xor(mx, 16));
      mx = fmaxf(mx, __shfl_xor(mx, 32));
      float sum = 0.f;
#pragma unroll
      for (int fj = 0; fj < 4; ++fj)
#pragma unroll
        for (int r = 0; r < 4; ++r) {
          float p = exp2f((S[fj][r] - mx) * 0.18033688011112f);  // log2(e)/8
          S[fj][r] = p;
          sum += p;
        }
      sum += __shfl_xor(sum, 16);
      sum += __shfl_xor(sum, 32);
      const float inv = 1.f / (11.f * sum);  // 1/11 lag-mean folded in

      // P split -> per-wave LDS bufs (hi, lo), XOR-swizzled
#pragma unroll
      for (int fj = 0; fj < 4; ++fj) {
        const int j0 = fj * 16 + g * 4;
        short4v ph, pl;
#pragma unroll
        for (int r = 0; r < 4; ++r) {
          u16 hh, ll;
          fsplit(S[fj][r] * inv, hh, ll);
          ph[r] = (short)hh;
          pl[r] = (short)ll;
        }
        const int chunk = (j0 >> 3) ^ (li & 7);
        const int boff = li * 128 + chunk * 16 + (j0 & 7) * 2;
        *(short4v*)(pbh + boff) = ph;
        *(short4v*)(pbl + boff) = pl;
      }

      // PV, 3-term: 24 MFMAs
#pragma unroll
      for (int ks = 0; ks < 2; ++ks) {
        const int poff = li * 128 + (((ks * 4 + g) ^ (li & 7)) * 16);
        bf16x8 pfh = *(const bf16x8*)(pbh + poff);
        bf16x8 pfl = *(const bf16x8*)(pbl + poff);
#pragma unroll
        for (int fc = 0; fc < 4; ++fc) {
          const int c = fc * 16 + li;
          const int off = c * 64 + (((ks * 4 + g) ^ (c & 7)) * 8);
          bf16x8 vh = *(const bf16x8*)(Vh + off);
          bf16x8 vl = *(const bf16x8*)(Vl + off);
          accO[fc] = MFMA(pfh, vh, accO[fc]);
          accO[fc] = MFMA(pfh, vl, accO[fc]);
          accO[fc] = MFMA(pfl, vh, accO[fc]);
        }
      }
      cur ^= 1;
    }
  }

  // Y split-write: wave w writes its own 16 rows; t<2 writes zeros
#pragma unroll
  for (int fc = 0; fc < 4; ++fc) {
    const int d = h * 64 + fc * 16 + li;
#pragma unroll
    for (int r = 0; r < 4; ++r) {
      const int i = i0 + g * 4 + r;
      u16 hh, ll;
      fsplit(accO[fc][r], hh, ll);
      const size_t idx = ((size_t)(t * 64 + i)) * 512 + d;
      Yhi[idx] = hh;
      Ylo[idx] = ll;
    }
  }
}

extern "C" void kernel_launch(void* const* d_in, const int* in_sizes, int n_in,
                              void* d_out, int out_size, void* d_ws, size_t ws_size,
                              hipStream_t stream) {
  (void)in_sizes; (void)n_in; (void)out_size; (void)ws_size;
  const float* x  = (const float*)d_in[0];
  const float* Wq = (const float*)d_in[1];
  const float* Wk = (const float*)d_in[2];
  const float* Wv = (const float*)d_in[3];
  const float* Wo = (const float*)d_in[4];
  // d_in[5] (lag_emb) is mathematically a no-op: constant shift along softmax axis.

  u16* ws = (u16*)d_ws;
  const size_t NX = 16777216u, NW = 262144u, NXB = 4194304u;  // NXB = NX/4 (one batch)
  // Workspace: 2NX + 8NW + 6NXB u16 = 116.0 MiB (< 130 MiB proven in rounds 2-6)
  u16* xhi  = ws;
  u16* xlo  = xhi + NX;
  u16* whi  = xlo + NX;       // [wq|wk|wv|wo] hi
  u16* wlo  = whi + 4 * NW;
  u16* qhi  = wlo + 4 * NW;   // per-batch; Y aliases Q after attention
  u16* qlo  = qhi + NXB;
  u16* khi  = qlo + NXB;
  u16* klo  = khi + NXB;
  u16* vthi = klo + NXB;
  u16* vtlo = vthi + NXB;

  CvtArgsP ca;
  ca.src[0] = x;  ca.dhi[0] = xhi;          ca.dlo[0] = xlo;
  ca.src[1] = Wq; ca.dhi[1] = whi;          ca.dlo[1] = wlo;
  ca.src[2] = Wk; ca.dhi[2] = whi + NW;     ca.dlo[2] = wlo + NW;
  ca.src[3] = Wv; ca.dhi[3] = whi + 2 * NW; ca.dlo[3] = wlo + 2 * NW;
  ca.src[4] = Wo; ca.dhi[4] = whi + 3 * NW; ca.dlo[4] = wlo + 3 * NW;
  convert_split_p<<<8704, 256, 0, stream>>>(ca);

  dim3 gb(64, 4);  // 8192/128 x 512/128 (one batch)
  for (int b = 0; b < 4; ++b) {
    const size_t bo = (size_t)b * NXB;
    gemm3_p<0><<<gb, 256, 0, stream>>>(xhi + bo, xlo + bo, whi, wlo, qhi, qlo);
    gemm3_p<0><<<gb, 256, 0, stream>>>(xhi + bo, xlo + bo, whi + NW, wlo + NW, khi, klo);
    gemm3_p<2><<<gb, 256, 0, stream>>>(xhi + bo, xlo + bo, whi + 2 * NW, wlo + 2 * NW, vthi, vtlo);
    attn_kernel_p<<<1024, 256, 0, stream>>>(qhi, qlo, khi, klo, vthi, vtlo, qhi, qlo);
    gemm3_p<1><<<gb, 256, 0, stream>>>(qhi, qlo, whi + 3 * NW, wlo + 3 * NW,
                                       (float*)d_out + bo, nullptr);
  }
}

// Round 15
// 629.555 us; speedup vs baseline: 1.1971x; 1.1971x over previous
//
#include <hip/hip_runtime.h>
#include <stdint.h>

typedef unsigned short u16;
typedef uint32_t u32;
typedef __attribute__((ext_vector_type(8))) short bf16x8;   // 8 bf16 (4 VGPRs)
typedef __attribute__((ext_vector_type(4))) float f32x4;
typedef __attribute__((ext_vector_type(4))) short short4v;
typedef __attribute__((ext_vector_type(8))) short short8v;
typedef __attribute__((ext_vector_type(4))) float float4v;

#define MFMA(a, b, c) __builtin_amdgcn_mfma_f32_16x16x32_bf16(a, b, c, 0, 0, 0)

__device__ __forceinline__ u16 f2bf(float f) {
  u32 u = __builtin_bit_cast(u32, f);
  u += 0x7FFFu + ((u >> 16) & 1u);  // RNE
  return (u16)(u >> 16);
}

// split: f ~= hi + lo, hi = truncated-bf16(f), lo = RNE-bf16(f - hi). |err| <= 2^-17 |f|
__device__ __forceinline__ void fsplit(float f, u16& hi, u16& lo) {
  u32 u = __builtin_bit_cast(u32, f);
  hi = (u16)(u >> 16);
  float fhi = __builtin_bit_cast(float, u & 0xFFFF0000u);
  lo = f2bf(f - fhi);  // exact subtraction (mantissa prefix)
}

__device__ __forceinline__ void load_lds16(const void* g, void* lds) {
  // width-16 direct global->LDS; dest = wave-uniform base, HW adds lane*16
  __builtin_amdgcn_global_load_lds((const __attribute__((address_space(1))) void*)g,
                                   (__attribute__((address_space(3))) void*)lds, 16, 0, 0);
}

// ---------------- convert fp32 -> (hi,lo) bf16 pair (x + 4 weights) ----------------
struct CvtArgsP {
  const float* src[5];
  u16* dhi[5];
  u16* dlo[5];
};

__global__ __launch_bounds__(256) void convert_split_p(CvtArgsP a) {
  const size_t NX = 16777216u;  // B*T*N*512
  const size_t NW = 262144u;    // 512*512
  size_t t8 = ((size_t)blockIdx.x * 256 + threadIdx.x) * 8;
  int seg;
  size_t off;
  if (t8 < NX) {
    seg = 0; off = t8;
  } else {
    size_t r = t8 - NX;
    seg = 1 + (int)(r >> 18);
    off = r & (NW - 1);
  }
  const float* s = a.src[seg] + off;
  float4v v0 = *((const float4v*)s);
  float4v v1 = *((const float4v*)(s + 4));
  short8v oh, ol;
  u16 h, l;
  fsplit(v0[0], h, l); oh[0] = (short)h; ol[0] = (short)l;
  fsplit(v0[1], h, l); oh[1] = (short)h; ol[1] = (short)l;
  fsplit(v0[2], h, l); oh[2] = (short)h; ol[2] = (short)l;
  fsplit(v0[3], h, l); oh[3] = (short)h; ol[3] = (short)l;
  fsplit(v1[0], h, l); oh[4] = (short)h; ol[4] = (short)l;
  fsplit(v1[1], h, l); oh[5] = (short)h; ol[5] = (short)l;
  fsplit(v1[2], h, l); oh[6] = (short)h; ol[6] = (short)l;
  fsplit(v1[3], h, l); oh[7] = (short)h; ol[7] = (short)l;
  *((short8v*)(a.dhi[seg] + off)) = oh;
  *((short8v*)(a.dlo[seg] + off)) = ol;
}

// ---------------- 3-term split-bf16 merged QKV GEMM (one batch, M=8192) ----------
// B = [Wq|Wk|Wv] (1536x512 contiguous, hi+lo). grid (64, 12), 768 blocks = 3/CU.
// 24 K-phases: kt 0-7 Ahi*Bhi, 8-15 Ahi*Blo, 16-23 Alo*Bhi (drop Alo*Blo ~2^-16).
// seg = n0g/512: 0 -> Q (hi,lo) row-major; 1 -> K (hi,lo) row-major; 2 -> v_t
// (hi,lo) layout v_t[bt][h][c][n] (bt = local t, h=col/64, c=col%64, n=m%64).
__global__ __launch_bounds__(256) void gemm3_qkv(const u16* __restrict__ Ahi,
                                                 const u16* __restrict__ Alo,
                                                 const u16* __restrict__ Bhi,
                                                 const u16* __restrict__ Blo,
                                                 u16* __restrict__ Cqh, u16* __restrict__ Cql,
                                                 u16* __restrict__ Ckh, u16* __restrict__ Ckl,
                                                 u16* __restrict__ Cvh, u16* __restrict__ Cvl) {
  __shared__ u16 lA[128 * 64];
  __shared__ u16 lB[128 * 64];
  const int tid = threadIdx.x;
  const int wave = tid >> 6, lane = tid & 63;
  const int g = lane >> 4, li = lane & 15;
  const int wr = wave >> 1, wc = wave & 1;
  const int m0 = blockIdx.x * 128;
  const int n0g = blockIdx.y * 128;          // 0..1408 over [Wq|Wk|Wv] rows
  const int seg = n0g >> 9, n0l = n0g & 511;
  const int rowa = tid >> 3, cl = tid & 7;

  f32x4 acc[4][4] = {};

  for (int kt = 0; kt < 24; ++kt) {
    const u16* As = (kt < 16) ? Ahi : Alo;
    const u16* Bs = (kt < 8) ? Bhi : ((kt < 16) ? Blo : Bhi);
    const int kk = (kt & 7) * 64;
    __syncthreads();
#pragma unroll
    for (int it = 0; it < 4; ++it) {
      const int r = it * 32 + rowa;
      const int sc = (cl ^ (r & 7)) * 8;  // pre-swizzled source chunk (rule #21)
      load_lds16(As + (size_t)(m0 + r) * 512 + kk + sc,
                 lA + (it * 256 + wave * 64) * 8);
      load_lds16(Bs + (size_t)(n0g + r) * 512 + kk + sc,
                 lB + (it * 256 + wave * 64) * 8);
    }
    __syncthreads();
#pragma unroll
    for (int ks = 0; ks < 2; ++ks) {
      bf16x8 af[4], bf[4];
#pragma unroll
      for (int mi = 0; mi < 4; ++mi) {
        const int r = wr * 64 + mi * 16 + li;
        af[mi] = *(const bf16x8*)(lA + r * 64 + (((ks * 4 + g) ^ (r & 7)) * 8));
      }
#pragma unroll
      for (int ni = 0; ni < 4; ++ni) {
        const int r = wc * 64 + ni * 16 + li;
        bf[ni] = *(const bf16x8*)(lB + r * 64 + (((ks * 4 + g) ^ (r & 7)) * 8));
      }
#pragma unroll
      for (int mi = 0; mi < 4; ++mi)
#pragma unroll
        for (int ni = 0; ni < 4; ++ni)
          acc[mi][ni] = MFMA(af[mi], bf[ni], acc[mi][ni]);
    }
  }

  if (seg < 2) {
    u16* Ch = (seg == 0) ? Cqh : Ckh;
    u16* Cl = (seg == 0) ? Cql : Ckl;
#pragma unroll
    for (int mi = 0; mi < 4; ++mi)
#pragma unroll
      for (int ni = 0; ni < 4; ++ni) {
        const int col = n0l + wc * 64 + ni * 16 + li;
        const int row0 = m0 + wr * 64 + mi * 16 + g * 4;
#pragma unroll
        for (int r = 0; r < 4; ++r) {
          u16 h, l;
          fsplit(acc[mi][ni][r], h, l);
          const size_t idx = (size_t)(row0 + r) * 512 + col;
          Ch[idx] = h;
          Cl[idx] = l;
        }
      }
  } else {
#pragma unroll
    for (int mi = 0; mi < 4; ++mi)
#pragma unroll
      for (int ni = 0; ni < 4; ++ni) {
        const int col = n0l + wc * 64 + ni * 16 + li;
        const int hh = col >> 6, c = col & 63;
        const int row0 = m0 + wr * 64 + mi * 16 + g * 4;
        const int bt = row0 >> 6, n = row0 & 63;   // bt = local t within batch
        short4v ph, pl;
#pragma unroll
        for (int r = 0; r < 4; ++r) {
          u16 h, l;
          fsplit(acc[mi][ni][r], h, l);
          ph[r] = (short)h;
          pl[r] = (short)l;
        }
        const size_t idx = ((size_t)bt * 8 + hh) * 4096 + (size_t)c * 64 + n;
        *(short4v*)(Cvh + idx) = ph;
        *(short4v*)(Cvl + idx) = pl;
      }
  }
}

// ---------------- 3-term split-bf16 out-proj: C fp32 = (Yhi+Ylo) * Wo^T ----------
__global__ __launch_bounds__(256) void gemm3_out(const u16* __restrict__ Ahi,
                                                 const u16* __restrict__ Alo,
                                                 const u16* __restrict__ Bhi,
                                                 const u16* __restrict__ Blo,
                                                 float* __restrict__ C) {
  __shared__ u16 lA[128 * 64];
  __shared__ u16 lB[128 * 64];
  const int tid = threadIdx.x;
  const int wave = tid >> 6, lane = tid & 63;
  const int g = lane >> 4, li = lane & 15;
  const int wr = wave >> 1, wc = wave & 1;
  const int m0 = blockIdx.x * 128, n0 = blockIdx.y * 128;
  const int rowa = tid >> 3, cl = tid & 7;

  f32x4 acc[4][4] = {};

  for (int kt = 0; kt < 24; ++kt) {
    const u16* As = (kt < 16) ? Ahi : Alo;
    const u16* Bs = (kt < 8) ? Bhi : ((kt < 16) ? Blo : Bhi);
    const int kk = (kt & 7) * 64;
    __syncthreads();
#pragma unroll
    for (int it = 0; it < 4; ++it) {
      const int r = it * 32 + rowa;
      const int sc = (cl ^ (r & 7)) * 8;
      load_lds16(As + (size_t)(m0 + r) * 512 + kk + sc,
                 lA + (it * 256 + wave * 64) * 8);
      load_lds16(Bs + (size_t)(n0 + r) * 512 + kk + sc,
                 lB + (it * 256 + wave * 64) * 8);
    }
    __syncthreads();
#pragma unroll
    for (int ks = 0; ks < 2; ++ks) {
      bf16x8 af[4], bf[4];
#pragma unroll
      for (int mi = 0; mi < 4; ++mi) {
        const int r = wr * 64 + mi * 16 + li;
        af[mi] = *(const bf16x8*)(lA + r * 64 + (((ks * 4 + g) ^ (r & 7)) * 8));
      }
#pragma unroll
      for (int ni = 0; ni < 4; ++ni) {
        const int r = wc * 64 + ni * 16 + li;
        bf[ni] = *(const bf16x8*)(lB + r * 64 + (((ks * 4 + g) ^ (r & 7)) * 8));
      }
#pragma unroll
      for (int mi = 0; mi < 4; ++mi)
#pragma unroll
        for (int ni = 0; ni < 4; ++ni)
          acc[mi][ni] = MFMA(af[mi], bf[ni], acc[mi][ni]);
    }
  }

#pragma unroll
  for (int mi = 0; mi < 4; ++mi)
#pragma unroll
    for (int ni = 0; ni < 4; ++ni) {
      const int col = n0 + wc * 64 + ni * 16 + li;
      const int row0 = m0 + wr * 64 + mi * 16 + g * 4;
#pragma unroll
      for (int r = 0; r < 4; ++r)
        C[(size_t)(row0 + r) * 512 + col] = acc[mi][ni][r];
    }
}

// ---------------- attention (ONE BATCH): one BLOCK per (t,h), waves split i ----
// Round-13 proven kernel, unchanged except Y now points at the dead x(b) slice
// (no aliasing with Q at all).
__global__ __launch_bounds__(256) void attn_kernel_p(const u16* __restrict__ qhi,
                                                     const u16* __restrict__ qlo,
                                                     const u16* __restrict__ khi,
                                                     const u16* __restrict__ klo,
                                                     const u16* __restrict__ vthi,
                                                     const u16* __restrict__ vtlo,
                                                     u16* __restrict__ Yhi,
                                                     u16* __restrict__ Ylo) {
  __shared__ __align__(16) char lds[81920];  // 2 x 32KB (Khi,Klo,Vhi,Vlo) dbuf + 4 x 4KB P(hi,lo)
  const int tid = threadIdx.x;
  const int wave = tid >> 6, lane = tid & 63;
  const int g = lane >> 4, li = lane & 15;
  const int bid = blockIdx.x;  // 0..1023
  const int h = bid & 7, t = bid >> 3;
  char* pbh = lds + 65536 + wave * 4096;
  char* pbl = pbh + 2048;
  const int i0 = wave * 16;
  const int sub = lane >> 3, cl = lane & 7;

  // Q fragments: lane(g,li) holds Q[i0+li][ks*32+g*8 + 0..7], hi and lo
  const size_t qoff = ((size_t)(t * 64 + i0 + li)) * 512 + h * 64;
  bf16x8 qfh[2], qfl[2];
#pragma unroll
  for (int ks = 0; ks < 2; ++ks) {
    qfh[ks] = *(const bf16x8*)(qhi + qoff + ks * 32 + g * 8);
    qfl[ks] = *(const bf16x8*)(qlo + qoff + ks * 32 + g * 8);
  }

  f32x4 accO[4] = {};  // [fc]; lane(g,li): O[i=i0+g*4+r][c=fc*16+li]
  const int lmax = (t < 12) ? t : 12;

  // stage: wave w loads array w (0:Khi 1:Klo 2:Vhi 3:Vlo), 8 chunks of 8 rows
  auto stage = [&](int st, int cur) {
    char* base = lds + cur * 32768 + wave * 8192;
    const u16* karr = (wave == 0) ? khi : klo;
    const u16* varr = (wave == 2) ? vthi : vtlo;
    const size_t koff = ((size_t)(st * 64)) * 512 + h * 64;
    const size_t voff = ((size_t)(st * 8 + h)) * 4096;
#pragma unroll
    for (int m = 0; m < 8; ++m) {
      const int r = m * 8 + sub;
      if (wave < 2) {  // K rows j = r, row stride 512
        load_lds16(karr + koff + (size_t)r * 512 + (cl ^ (r & 7)) * 8,
                   base + m * 1024);
      } else {         // V^T rows c = r, contiguous 4096
        load_lds16(varr + voff + r * 64 + (cl ^ (r & 7)) * 8,
                   base + m * 1024);
      }
    }
  };

  if (lmax >= 2) {
    stage(t - 2, 0);
    int cur = 0;
    for (int lag = 2; lag <= lmax; ++lag) {
      __syncthreads();  // drains each wave's staging loads + syncs buffers
      if (lag < lmax) stage(t - lag - 1, cur ^ 1);  // prefetch next under compute

      const u16* Kh = (const u16*)(lds + cur * 32768);
      const u16* Kl = Kh + 4096;
      const u16* Vh = Kh + 8192;
      const u16* Vl = Kh + 12288;

      // S^T, 3-term: 24 MFMAs
      f32x4 S[4] = {};
#pragma unroll
      for (int ks = 0; ks < 2; ++ks)
#pragma unroll
        for (int fj = 0; fj < 4; ++fj) {
          const int j = fj * 16 + li;
          const int off = j * 64 + (((ks * 4 + g) ^ (j & 7)) * 8);
          bf16x8 kh = *(const bf16x8*)(Kh + off);
          bf16x8 kl = *(const bf16x8*)(Kl + off);
          S[fj] = MFMA(kh, qfh[ks], S[fj]);
          S[fj] = MFMA(kl, qfh[ks], S[fj]);
          S[fj] = MFMA(kh, qfl[ks], S[fj]);
        }

      // row softmax over j (round-6 proven path)
      float mx = S[0][0];
#pragma unroll
      for (int fj = 0; fj < 4; ++fj)
#pragma unroll
        for (int r = 0; r < 4; ++r) mx = fmaxf(mx, S[fj][r]);
      mx = fmaxf(mx, __shfl_xor(mx, 16));
      mx = fmaxf(mx, __shfl_xor(mx, 32));
      float sum = 0.f;
#pragma unroll
      for (int fj = 0; fj < 4; ++fj)
#pragma unroll
        for (int r = 0; r < 4; ++r) {
          float p = exp2f((S[fj][r] - mx) * 0.18033688011112f);  // log2(e)/8
          S[fj][r] = p;
          sum += p;
        }
      sum += __shfl_xor(sum, 16);
      sum += __shfl_xor(sum, 32);
      const float inv = 1.f / (11.f * sum);  // 1/11 lag-mean folded in

      // P split -> per-wave LDS bufs (hi, lo), XOR-swizzled
#pragma unroll
      for (int fj = 0; fj < 4; ++fj) {
        const int j0 = fj * 16 + g * 4;
        short4v ph, pl;
#pragma unroll
        for (int r = 0; r < 4; ++r) {
          u16 hh, ll;
          fsplit(S[fj][r] * inv, hh, ll);
          ph[r] = (short)hh;
          pl[r] = (short)ll;
        }
        const int chunk = (j0 >> 3) ^ (li & 7);
        const int boff = li * 128 + chunk * 16 + (j0 & 7) * 2;
        *(short4v*)(pbh + boff) = ph;
        *(short4v*)(pbl + boff) = pl;
      }

      // PV, 3-term: 24 MFMAs
#pragma unroll
      for (int ks = 0; ks < 2; ++ks) {
        const int poff = li * 128 + (((ks * 4 + g) ^ (li & 7)) * 16);
        bf16x8 pfh = *(const bf16x8*)(pbh + poff);
        bf16x8 pfl = *(const bf16x8*)(pbl + poff);
#pragma unroll
        for (int fc = 0; fc < 4; ++fc) {
          const int c = fc * 16 + li;
          const int off = c * 64 + (((ks * 4 + g) ^ (c & 7)) * 8);
          bf16x8 vh = *(const bf16x8*)(Vh + off);
          bf16x8 vl = *(const bf16x8*)(Vl + off);
          accO[fc] = MFMA(pfh, vh, accO[fc]);
          accO[fc] = MFMA(pfh, vl, accO[fc]);
          accO[fc] = MFMA(pfl, vh, accO[fc]);
        }
      }
      cur ^= 1;
    }
  }

  // Y split-write: wave w writes its own 16 rows; t<2 writes zeros
#pragma unroll
  for (int fc = 0; fc < 4; ++fc) {
    const int d = h * 64 + fc * 16 + li;
#pragma unroll
    for (int r = 0; r < 4; ++r) {
      const int i = i0 + g * 4 + r;
      u16 hh, ll;
      fsplit(accO[fc][r], hh, ll);
      const size_t idx = ((size_t)(t * 64 + i)) * 512 + d;
      Yhi[idx] = hh;
      Ylo[idx] = ll;
    }
  }
}

extern "C" void kernel_launch(void* const* d_in, const int* in_sizes, int n_in,
                              void* d_out, int out_size, void* d_ws, size_t ws_size,
                              hipStream_t stream) {
  (void)in_sizes; (void)n_in; (void)out_size; (void)ws_size;
  const float* x  = (const float*)d_in[0];
  const float* Wq = (const float*)d_in[1];
  const float* Wk = (const float*)d_in[2];
  const float* Wv = (const float*)d_in[3];
  const float* Wo = (const float*)d_in[4];
  // d_in[5] (lag_emb) is mathematically a no-op: constant shift along softmax axis.

  u16* ws = (u16*)d_ws;
  const size_t NX = 16777216u, NW = 262144u, NXB = 4194304u;  // NXB = NX/4 (one batch)
  // Workspace: 2NX + 8NW + 6NXB u16 = 116.0 MiB (< 130 MiB proven)
  u16* xhi  = ws;             // x(b) slice becomes Y(b) after gemm3_qkv(b) consumes it
  u16* xlo  = xhi + NX;
  u16* whi  = xlo + NX;       // [wq|wk|wv|wo] hi (wq|wk|wv rows 0-1535 feed merged QKV)
  u16* wlo  = whi + 4 * NW;
  u16* qhi  = wlo + 4 * NW;   // per-batch
  u16* qlo  = qhi + NXB;
  u16* khi  = qlo + NXB;
  u16* klo  = khi + NXB;
  u16* vthi = klo + NXB;
  u16* vtlo = vthi + NXB;

  CvtArgsP ca;
  ca.src[0] = x;  ca.dhi[0] = xhi;          ca.dlo[0] = xlo;
  ca.src[1] = Wq; ca.dhi[1] = whi;          ca.dlo[1] = wlo;
  ca.src[2] = Wk; ca.dhi[2] = whi + NW;     ca.dlo[2] = wlo + NW;
  ca.src[3] = Wv; ca.dhi[3] = whi + 2 * NW; ca.dlo[3] = wlo + 2 * NW;
  ca.src[4] = Wo; ca.dhi[4] = whi + 3 * NW; ca.dlo[4] = wlo + 3 * NW;
  convert_split_p<<<8704, 256, 0, stream>>>(ca);

  dim3 gq(64, 12);  // 8192/128 x 1536/128 (merged QKV, 3 blocks/CU)
  dim3 go(64, 4);   // 8192/128 x 512/128 (out-proj)
  for (int b = 0; b < 4; ++b) {
    const size_t bo = (size_t)b * NXB;
    gemm3_qkv<<<gq, 256, 0, stream>>>(xhi + bo, xlo + bo, whi, wlo,
                                      qhi, qlo, khi, klo, vthi, vtlo);
    // x(b) is dead now; its slice becomes Y(b)
    attn_kernel_p<<<1024, 256, 0, stream>>>(qhi, qlo, khi, klo, vthi, vtlo,
                                            xhi + bo, xlo + bo);
    gemm3_out<<<go, 256, 0, stream>>>(xhi + bo, xlo + bo, whi + 3 * NW, wlo + 3 * NW,
                                      (float*)d_out + bo);
  }
}